// Round 1
// baseline (508.460 us; speedup 1.0000x reference)
//
#include <hip/hip_runtime.h>
#include <math.h>

#define N_NODES 10000
#define B_BATCH 4
#define F_IN_C 128
#define HID_C 64
#define HEADS_C 4
#define E_EDGES 160000
#define E_TOT (E_EDGES + N_NODES)
#define NEG_SLOPE 0.2f

// ---------------- CSR construction (edge structure shared across batches/layers) ----------------

__global__ void k_deg_init(int* __restrict__ deg) {
    int i = blockIdx.x * 256 + threadIdx.x;
    if (i < N_NODES) deg[i] = 1;  // self loop
}

__global__ void k_deg_count(const int* __restrict__ ei, int* __restrict__ deg) {
    int e = blockIdx.x * 256 + threadIdx.x;
    if (e < E_EDGES) atomicAdd(&deg[ei[E_EDGES + e]], 1);
}

__global__ void k_scan(const int* __restrict__ deg, int* __restrict__ offs, int* __restrict__ cursor) {
    __shared__ int lds[1024];
    __shared__ int carry_s;
    int tid = threadIdx.x;
    if (tid == 0) { carry_s = 0; offs[0] = 0; }
    __syncthreads();
    for (int base = 0; base < N_NODES; base += 1024) {
        int i = base + tid;
        int v = (i < N_NODES) ? deg[i] : 0;
        lds[tid] = v;
        __syncthreads();
        for (int ofs = 1; ofs < 1024; ofs <<= 1) {
            int t = (tid >= ofs) ? lds[tid - ofs] : 0;
            __syncthreads();
            lds[tid] += t;
            __syncthreads();
        }
        int carry = carry_s;
        if (i < N_NODES) offs[i + 1] = carry + lds[tid];
        __syncthreads();
        if (tid == 1023) carry_s = carry + lds[1023];
        __syncthreads();
    }
    for (int i = tid; i < N_NODES; i += 1024) cursor[i] = offs[i];
}

__global__ void k_scatter(const int* __restrict__ ei, int* __restrict__ cursor, int* __restrict__ csr_src) {
    int e = blockIdx.x * 256 + threadIdx.x;
    if (e < E_TOT) {
        int s, d;
        if (e < E_EDGES) { s = ei[e]; d = ei[E_EDGES + e]; }
        else { s = d = e - E_EDGES; }
        int pos = atomicAdd(&cursor[d], 1);
        csr_src[pos] = s;
    }
}

// ---------------- Fused GEMM: h = x@W, al_src/al_dst via wave reduce ----------------
// Block: 256 threads = 4 waves; wave w covers output cols [64w, 64w+64) == head w.
// 8 nodes per block.

template <int K>
__launch_bounds__(256)
__global__ void k_gemm(const float* __restrict__ x, const float* __restrict__ W,
                       const float* __restrict__ a_src, const float* __restrict__ a_dst,
                       float* __restrict__ h, float* __restrict__ alsrc, float* __restrict__ aldst) {
    __shared__ float xs[8][K];
    int tid = threadIdx.x;
    int b = blockIdx.y;
    int node0 = blockIdx.x * 8;
    const float* xb = x + (size_t)b * N_NODES * K;
    for (int idx = tid; idx < 8 * K; idx += 256) {
        int i = idx / K, k = idx % K;
        int n = node0 + i;
        xs[i][k] = (n < N_NODES) ? xb[(size_t)n * K + k] : 0.f;
    }
    __syncthreads();
    float acc[8] = {0, 0, 0, 0, 0, 0, 0, 0};
    for (int k = 0; k < K; k++) {
        float w = W[k * 256 + tid];
#pragma unroll
        for (int i = 0; i < 8; i++) acc[i] += xs[i][k] * w;
    }
    float as = a_src[tid], ad = a_dst[tid];
    int hh = tid >> 6, lane = tid & 63;
    size_t nb = (size_t)b * N_NODES;
#pragma unroll
    for (int i = 0; i < 8; i++) {
        int n = node0 + i;
        if (n >= N_NODES) break;
        float hv = acc[i];
        h[(nb + n) * 256 + tid] = hv;
        float vs = hv * as, vd = hv * ad;
        for (int o = 32; o > 0; o >>= 1) {
            vs += __shfl_xor(vs, o, 64);
            vd += __shfl_xor(vd, o, 64);
        }
        if (lane == 0) {
            alsrc[(nb + n) * 4 + hh] = vs;
            aldst[(nb + n) * 4 + hh] = vd;
        }
    }
}

// ---------------- Segment softmax stats: one thread per (dst, head) ----------------

__launch_bounds__(256)
__global__ void k_ms(const float* __restrict__ alsrc, const float* __restrict__ aldst,
                     const int* __restrict__ offs, const int* __restrict__ csr,
                     float* __restrict__ m_arr, float* __restrict__ s_arr) {
    int t = blockIdx.x * 256 + threadIdx.x;
    if (t >= N_NODES * HEADS_C) return;
    int dst = t >> 2, hh = t & 3;
    int b = blockIdx.y;
    size_t nb = (size_t)b * N_NODES;
    const float* als = alsrc + nb * 4;
    float ad = aldst[(nb + dst) * 4 + hh];
    int s0 = offs[dst], s1 = offs[dst + 1];
    float m = -1e30f;
    for (int j = s0; j < s1; j++) {
        float a = als[csr[j] * 4 + hh] + ad;
        a = a > 0.f ? a : NEG_SLOPE * a;
        m = fmaxf(m, a);
    }
    float s = 0.f;
    for (int j = s0; j < s1; j++) {
        float a = als[csr[j] * 4 + hh] + ad;
        a = a > 0.f ? a : NEG_SLOPE * a;
        s += __expf(a - m);
    }
    m_arr[(nb + dst) * 4 + hh] = m;
    s_arr[(nb + dst) * 4 + hh] = s;
}

// ---------------- Aggregation: block per (dst, batch); thread = (head, chan) ----------------

template <bool LAYER1>
__launch_bounds__(256)
__global__ void k_agg(const float* __restrict__ h_arr, const float* __restrict__ alsrc,
                      const float* __restrict__ aldst, const float* __restrict__ m_arr,
                      const float* __restrict__ s_arr, const int* __restrict__ offs,
                      const int* __restrict__ csr, const float* __restrict__ bias,
                      float* __restrict__ out) {
    __shared__ float red[256];
    int tid = threadIdx.x;
    int dst = blockIdx.x;
    int b = blockIdx.y;
    int hh = tid >> 6;
    size_t nb = (size_t)b * N_NODES;
    float m = m_arr[(nb + dst) * 4 + hh];
    float s = s_arr[(nb + dst) * 4 + hh];
    float ad = aldst[(nb + dst) * 4 + hh];
    const float* als = alsrc + nb * 4;
    const float* hb = h_arr + nb * 256;
    int s0 = offs[dst], s1 = offs[dst + 1];
    float acc = 0.f;
    for (int j = s0; j < s1; j++) {
        int src = csr[j];
        float a = als[src * 4 + hh] + ad;
        a = a > 0.f ? a : NEG_SLOPE * a;
        float p = __expf(a - m);
        acc += p * hb[(size_t)src * 256 + tid];
    }
    acc /= (s + 1e-16f);
    red[tid] = acc;
    __syncthreads();
    if (tid < 64) {
        float o = (red[tid] + red[tid + 64] + red[tid + 128] + red[tid + 192]) * 0.25f + bias[tid];
        if (LAYER1) o = o > 0.f ? o : expm1f(o);
        out[(nb + dst) * 64 + tid] = o;
    }
}

// ---------------- Launch ----------------

extern "C" void kernel_launch(void* const* d_in, const int* in_sizes, int n_in,
                              void* d_out, int out_size, void* d_ws, size_t ws_size,
                              hipStream_t stream) {
    const float* x = (const float*)d_in[0];
    const int* ei = (const int*)d_in[1];
    const float* W1 = (const float*)d_in[2];
    const float* as1 = (const float*)d_in[3];
    const float* ad1 = (const float*)d_in[4];
    const float* b1 = (const float*)d_in[5];
    const float* W2 = (const float*)d_in[6];
    const float* as2 = (const float*)d_in[7];
    const float* ad2 = (const float*)d_in[8];
    const float* b2 = (const float*)d_in[9];
    float* out = (float*)d_out;

    // workspace layout
    char* p = (char*)d_ws;
    int* deg = (int*)p;            p += sizeof(int) * N_NODES;
    int* offs = (int*)p;           p += sizeof(int) * (N_NODES + 1);
    int* cursor = (int*)p;         p += sizeof(int) * N_NODES;
    int* csr = (int*)p;            p += sizeof(int) * E_TOT;
    float* alsrc = (float*)p;      p += sizeof(float) * B_BATCH * N_NODES * 4;
    float* aldst = (float*)p;      p += sizeof(float) * B_BATCH * N_NODES * 4;
    float* m_arr = (float*)p;      p += sizeof(float) * B_BATCH * N_NODES * 4;
    float* s_arr = (float*)p;      p += sizeof(float) * B_BATCH * N_NODES * 4;
    float* h = (float*)p;          p += sizeof(float) * (size_t)B_BATCH * N_NODES * 256;
    float* x2 = (float*)p;         p += sizeof(float) * (size_t)B_BATCH * N_NODES * 64;

    // CSR build
    k_deg_init<<<(N_NODES + 255) / 256, 256, 0, stream>>>(deg);
    k_deg_count<<<(E_EDGES + 255) / 256, 256, 0, stream>>>(ei, deg);
    k_scan<<<1, 1024, 0, stream>>>(deg, offs, cursor);
    k_scatter<<<(E_TOT + 255) / 256, 256, 0, stream>>>(ei, cursor, csr);

    dim3 gGemm(N_NODES / 8, B_BATCH);
    dim3 gMs((N_NODES * HEADS_C + 255) / 256, B_BATCH);
    dim3 gAgg(N_NODES, B_BATCH);

    // Layer 1
    k_gemm<F_IN_C><<<gGemm, 256, 0, stream>>>(x, W1, as1, ad1, h, alsrc, aldst);
    k_ms<<<gMs, 256, 0, stream>>>(alsrc, aldst, offs, csr, m_arr, s_arr);
    k_agg<true><<<gAgg, 256, 0, stream>>>(h, alsrc, aldst, m_arr, s_arr, offs, csr, b1, x2);

    // Layer 2
    k_gemm<HID_C><<<gGemm, 256, 0, stream>>>(x2, W2, as2, ad2, h, alsrc, aldst);
    k_ms<<<gMs, 256, 0, stream>>>(alsrc, aldst, offs, csr, m_arr, s_arr);
    k_agg<false><<<gAgg, 256, 0, stream>>>(h, alsrc, aldst, m_arr, s_arr, offs, csr, b2, out);
}

// Round 2
// 313.270 us; speedup vs baseline: 1.6231x; 1.6231x over previous
//
#include <hip/hip_runtime.h>
#include <math.h>

#define N_NODES 10000
#define B_BATCH 4
#define F_IN_C 128
#define HID_C 64
#define HEADS_C 4
#define E_EDGES 160000
#define E_TOT (E_EDGES + N_NODES)
#define NEG_SLOPE 0.2f

// ---------------- CSR construction (edge structure shared across batches/layers) ----------------

__global__ void k_deg_init(int* __restrict__ deg) {
    int i = blockIdx.x * 256 + threadIdx.x;
    if (i < N_NODES) deg[i] = 1;  // self loop
}

__global__ void k_deg_count(const int* __restrict__ ei, int* __restrict__ deg) {
    int e = blockIdx.x * 256 + threadIdx.x;
    if (e < E_EDGES) atomicAdd(&deg[ei[E_EDGES + e]], 1);
}

// 1024 threads, 10 serial elems/thread, single LDS scan.
__global__ void k_scan(const int* __restrict__ deg, int* __restrict__ offs, int* __restrict__ cursor) {
    __shared__ int lds[1024];
    int t = threadIdx.x;
    int local[10];
    int tot = 0;
#pragma unroll
    for (int j = 0; j < 10; j++) {
        int i = t * 10 + j;
        int v = (i < N_NODES) ? deg[i] : 0;
        tot += v;
        local[j] = tot;  // inclusive within chunk
    }
    lds[t] = tot;
    __syncthreads();
    for (int ofs = 1; ofs < 1024; ofs <<= 1) {
        int v = (t >= ofs) ? lds[t - ofs] : 0;
        __syncthreads();
        lds[t] += v;
        __syncthreads();
    }
    int base = lds[t] - tot;  // exclusive prefix of this chunk
#pragma unroll
    for (int j = 0; j < 10; j++) {
        int i = t * 10 + j;
        if (i < N_NODES) {
            offs[i + 1] = base + local[j];
            cursor[i] = (j == 0) ? base : base + local[j - 1];
        }
    }
    if (t == 0) offs[0] = 0;
}

__global__ void k_scatter(const int* __restrict__ ei, int* __restrict__ cursor, int* __restrict__ csr_src) {
    int e = blockIdx.x * 256 + threadIdx.x;
    if (e < E_TOT) {
        int s, d;
        if (e < E_EDGES) { s = ei[e]; d = ei[E_EDGES + e]; }
        else { s = d = e - E_EDGES; }
        int pos = atomicAdd(&cursor[d], 1);
        csr_src[pos] = s;
    }
}

// ---------------- Fused GEMM: h = x@W, al_src/al_dst via wave reduce ----------------
// 256 threads = 4 groups of 64 lanes. Lane l covers cols 4l..4l+3 (float4 W).
// Group g handles nodes node0 + 4g .. +3. 16 nodes/block.

template <int K>
__launch_bounds__(256)
__global__ void k_gemm(const float* __restrict__ x, const float* __restrict__ W,
                       const float* __restrict__ a_src, const float* __restrict__ a_dst,
                       float* __restrict__ h, float* __restrict__ alsrc, float* __restrict__ aldst) {
    __shared__ float xs[16][K + 4];
    int t = threadIdx.x;
    int g = t >> 6, lane = t & 63;
    int b = blockIdx.y;
    int node0 = blockIdx.x * 16;
    const float* xb = x + (size_t)b * N_NODES * K;
    // stage 16 node rows, float4
    for (int idx = t; idx < 16 * K / 4; idx += 256) {
        int n = idx / (K / 4), kk = idx % (K / 4);
        float4 v = *(const float4*)(xb + (size_t)(node0 + n) * K + kk * 4);
        *(float4*)(&xs[n][kk * 4]) = v;
    }
    __syncthreads();

    float4 acc[4];
#pragma unroll
    for (int i = 0; i < 4; i++) acc[i] = make_float4(0.f, 0.f, 0.f, 0.f);

    for (int k = 0; k < K; k++) {
        float4 w4 = *(const float4*)(W + (size_t)k * 256 + lane * 4);
#pragma unroll
        for (int i = 0; i < 4; i++) {
            float xv = xs[g * 4 + i][k];
            acc[i].x += xv * w4.x;
            acc[i].y += xv * w4.y;
            acc[i].z += xv * w4.z;
            acc[i].w += xv * w4.w;
        }
    }

    float4 as4 = *(const float4*)(a_src + lane * 4);
    float4 ad4 = *(const float4*)(a_dst + lane * 4);
    int hd = lane >> 4;
    size_t nb = (size_t)b * N_NODES;
#pragma unroll
    for (int i = 0; i < 4; i++) {
        int n = node0 + g * 4 + i;
        *(float4*)(h + (nb + n) * 256 + lane * 4) = acc[i];
        float vs = acc[i].x * as4.x + acc[i].y * as4.y + acc[i].z * as4.z + acc[i].w * as4.w;
        float vd = acc[i].x * ad4.x + acc[i].y * ad4.y + acc[i].z * ad4.z + acc[i].w * ad4.w;
#pragma unroll
        for (int o = 1; o < 16; o <<= 1) {
            vs += __shfl_xor(vs, o);
            vd += __shfl_xor(vd, o);
        }
        if ((lane & 15) == 0) {
            alsrc[(nb + n) * 4 + hd] = vs;
            aldst[(nb + n) * 4 + hd] = vd;
        }
    }
}

// ---------------- Fused softmax + aggregation: one wave per (dst, batch) ----------------
// Lane l covers channels 4l..4l+3; head = l>>4. Pass 1: strided max. Pass 2: gather+sum.

template <bool LAYER1>
__launch_bounds__(256)
__global__ void k_agg(const float* __restrict__ h_arr, const float* __restrict__ alsrc,
                      const float* __restrict__ aldst, const int* __restrict__ offs,
                      const int* __restrict__ csr, const float* __restrict__ bias,
                      float* __restrict__ out) {
    int t = threadIdx.x;
    int w = t >> 6, lane = t & 63;
    int dst = blockIdx.x * 4 + w;
    int b = blockIdx.y;
    size_t nb = (size_t)b * N_NODES;
    const float* als = alsrc + nb * 4;
    const float* hb = h_arr + nb * 256;

    float4 ad4 = *(const float4*)(aldst + (nb + dst) * 4);
    int s0 = offs[dst], s1 = offs[dst + 1];

    // pass 1: per-head max of leaky(al_src[src] + al_dst[dst]) over edges (strided over lanes)
    float m0 = -1e30f, m1 = -1e30f, m2 = -1e30f, m3 = -1e30f;
    for (int j = s0 + lane; j < s1; j += 64) {
        int src = csr[j];
        float4 a4 = *(const float4*)(als + (size_t)src * 4);
        float a;
        a = a4.x + ad4.x; a = a > 0.f ? a : NEG_SLOPE * a; m0 = fmaxf(m0, a);
        a = a4.y + ad4.y; a = a > 0.f ? a : NEG_SLOPE * a; m1 = fmaxf(m1, a);
        a = a4.z + ad4.z; a = a > 0.f ? a : NEG_SLOPE * a; m2 = fmaxf(m2, a);
        a = a4.w + ad4.w; a = a > 0.f ? a : NEG_SLOPE * a; m3 = fmaxf(m3, a);
    }
#pragma unroll
    for (int o = 32; o > 0; o >>= 1) {
        m0 = fmaxf(m0, __shfl_xor(m0, o));
        m1 = fmaxf(m1, __shfl_xor(m1, o));
        m2 = fmaxf(m2, __shfl_xor(m2, o));
        m3 = fmaxf(m3, __shfl_xor(m3, o));
    }

    int hd = lane >> 4;
    float m_h = hd == 0 ? m0 : hd == 1 ? m1 : hd == 2 ? m2 : m3;
    float ad_h = hd == 0 ? ad4.x : hd == 1 ? ad4.y : hd == 2 ? ad4.z : ad4.w;

    // pass 2: every lane walks all edges; p identical within 16-lane head group
    float4 acc = make_float4(0.f, 0.f, 0.f, 0.f);
    float sacc = 0.f;
    for (int j = s0; j < s1; j++) {
        int src = csr[j];
        float a = als[(size_t)src * 4 + hd] + ad_h;
        a = a > 0.f ? a : NEG_SLOPE * a;
        float p = __expf(a - m_h);
        float4 h4 = *(const float4*)(hb + (size_t)src * 256 + lane * 4);
        acc.x += p * h4.x;
        acc.y += p * h4.y;
        acc.z += p * h4.z;
        acc.w += p * h4.w;
        sacc += p;
    }
    float inv = 1.f / (sacc + 1e-16f);
    acc.x *= inv; acc.y *= inv; acc.z *= inv; acc.w *= inv;

    // head mean: lanes {l, l^16, l^32, l^48} hold same channel group, heads 0..3
#pragma unroll
    for (int o = 16; o < 64; o <<= 1) {
        acc.x += __shfl_xor(acc.x, o);
        acc.y += __shfl_xor(acc.y, o);
        acc.z += __shfl_xor(acc.z, o);
        acc.w += __shfl_xor(acc.w, o);
    }
    if (lane < 16) {
        float4 b4 = *(const float4*)(bias + lane * 4);
        float ox = acc.x * 0.25f + b4.x;
        float oy = acc.y * 0.25f + b4.y;
        float oz = acc.z * 0.25f + b4.z;
        float ow = acc.w * 0.25f + b4.w;
        if (LAYER1) {
            ox = ox > 0.f ? ox : expm1f(ox);
            oy = oy > 0.f ? oy : expm1f(oy);
            oz = oz > 0.f ? oz : expm1f(oz);
            ow = ow > 0.f ? ow : expm1f(ow);
        }
        *(float4*)(out + (nb + dst) * 64 + lane * 4) = make_float4(ox, oy, oz, ow);
    }
}

// ---------------- Launch ----------------

extern "C" void kernel_launch(void* const* d_in, const int* in_sizes, int n_in,
                              void* d_out, int out_size, void* d_ws, size_t ws_size,
                              hipStream_t stream) {
    const float* x = (const float*)d_in[0];
    const int* ei = (const int*)d_in[1];
    const float* W1 = (const float*)d_in[2];
    const float* as1 = (const float*)d_in[3];
    const float* ad1 = (const float*)d_in[4];
    const float* b1 = (const float*)d_in[5];
    const float* W2 = (const float*)d_in[6];
    const float* as2 = (const float*)d_in[7];
    const float* ad2 = (const float*)d_in[8];
    const float* b2 = (const float*)d_in[9];
    float* out = (float*)d_out;

    // workspace layout
    char* p = (char*)d_ws;
    int* deg = (int*)p;            p += sizeof(int) * N_NODES;
    int* offs = (int*)p;           p += sizeof(int) * (N_NODES + 1);
    int* cursor = (int*)p;         p += sizeof(int) * N_NODES;
    int* csr = (int*)p;            p += sizeof(int) * E_TOT;
    float* alsrc = (float*)p;      p += sizeof(float) * B_BATCH * N_NODES * 4;
    float* aldst = (float*)p;      p += sizeof(float) * B_BATCH * N_NODES * 4;
    float* h = (float*)p;          p += sizeof(float) * (size_t)B_BATCH * N_NODES * 256;
    float* x2 = (float*)p;         p += sizeof(float) * (size_t)B_BATCH * N_NODES * 64;

    // CSR build
    k_deg_init<<<(N_NODES + 255) / 256, 256, 0, stream>>>(deg);
    k_deg_count<<<(E_EDGES + 255) / 256, 256, 0, stream>>>(ei, deg);
    k_scan<<<1, 1024, 0, stream>>>(deg, offs, cursor);
    k_scatter<<<(E_TOT + 255) / 256, 256, 0, stream>>>(ei, cursor, csr);

    dim3 gGemm(N_NODES / 16, B_BATCH);
    dim3 gAgg(N_NODES / 4, B_BATCH);

    // Layer 1
    k_gemm<F_IN_C><<<gGemm, 256, 0, stream>>>(x, W1, as1, ad1, h, alsrc, aldst);
    k_agg<true><<<gAgg, 256, 0, stream>>>(h, alsrc, aldst, offs, csr, b1, x2);

    // Layer 2
    k_gemm<HID_C><<<gGemm, 256, 0, stream>>>(x2, W2, as2, ad2, h, alsrc, aldst);
    k_agg<false><<<gAgg, 256, 0, stream>>>(h, alsrc, aldst, offs, csr, b2, out);
}

// Round 3
// 259.467 us; speedup vs baseline: 1.9596x; 1.2074x over previous
//
#include <hip/hip_runtime.h>
#include <math.h>

#define N_NODES 10000
#define B_BATCH 4
#define F_IN_C 128
#define HID_C 64
#define HEADS_C 4
#define E_EDGES 160000
#define E_TOT (E_EDGES + N_NODES)
#define NEG_SLOPE 0.2f

// ---------------- CSR construction (edge structure shared across batches/layers) ----------------

__global__ void k_deg_init(int* __restrict__ deg) {
    int i = blockIdx.x * 256 + threadIdx.x;
    if (i < N_NODES) deg[i] = 1;  // self loop
}

__global__ void k_deg_count(const int* __restrict__ ei, int* __restrict__ deg) {
    int e = blockIdx.x * 256 + threadIdx.x;
    if (e < E_EDGES) atomicAdd(&deg[ei[E_EDGES + e]], 1);
}

// 1024 threads, 10 serial elems/thread, single LDS scan.
__global__ void k_scan(const int* __restrict__ deg, int* __restrict__ offs, int* __restrict__ cursor) {
    __shared__ int lds[1024];
    int t = threadIdx.x;
    int local[10];
    int tot = 0;
#pragma unroll
    for (int j = 0; j < 10; j++) {
        int i = t * 10 + j;
        int v = (i < N_NODES) ? deg[i] : 0;
        tot += v;
        local[j] = tot;  // inclusive within chunk
    }
    lds[t] = tot;
    __syncthreads();
    for (int ofs = 1; ofs < 1024; ofs <<= 1) {
        int v = (t >= ofs) ? lds[t - ofs] : 0;
        __syncthreads();
        lds[t] += v;
        __syncthreads();
    }
    int base = lds[t] - tot;  // exclusive prefix of this chunk
#pragma unroll
    for (int j = 0; j < 10; j++) {
        int i = t * 10 + j;
        if (i < N_NODES) {
            offs[i + 1] = base + local[j];
            cursor[i] = (j == 0) ? base : base + local[j - 1];
        }
    }
    if (t == 0) offs[0] = 0;
}

__global__ void k_scatter(const int* __restrict__ ei, int* __restrict__ cursor, int* __restrict__ csr_src) {
    int e = blockIdx.x * 256 + threadIdx.x;
    if (e < E_TOT) {
        int s, d;
        if (e < E_EDGES) { s = ei[e]; d = ei[E_EDGES + e]; }
        else { s = d = e - E_EDGES; }
        int pos = atomicAdd(&cursor[d], 1);
        csr_src[pos] = s;
    }
}

// ---------------- Fused GEMM: h = x@W (head-major store), al_src/al_dst via group reduce --------
// 256 threads = 4 waves; wave wv handles nodes node0+wv*8 .. +7 (32 nodes/block).
// Lane l covers cols 4l..4l+3. W staged through LDS in 32-row chunks.

template <int K>
__launch_bounds__(256)
__global__ void k_gemm(const float* __restrict__ x, const float* __restrict__ W,
                       const float* __restrict__ a_src, const float* __restrict__ a_dst,
                       float* __restrict__ h2, float* __restrict__ alsrc, float* __restrict__ aldst) {
    __shared__ float xs[32][K];
    __shared__ float Ws[32][256];
    int t = threadIdx.x;
    int wv = t >> 6, lane = t & 63;
    int b = blockIdx.y;
    int node0 = blockIdx.x * 32;
    const float* xb = x + (size_t)b * N_NODES * K;

    for (int idx = t; idx < 32 * (K / 4); idx += 256) {
        int r = idx / (K / 4), c4 = idx % (K / 4);
        int n = node0 + r;
        if (n > N_NODES - 1) n = N_NODES - 1;
        *(float4*)&xs[r][c4 * 4] = *(const float4*)(xb + (size_t)n * K + c4 * 4);
    }

    float4 acc[8];
#pragma unroll
    for (int i = 0; i < 8; i++) acc[i] = make_float4(0.f, 0.f, 0.f, 0.f);

    for (int k0 = 0; k0 < K; k0 += 32) {
        __syncthreads();
        for (int idx = t; idx < 32 * 64; idx += 256) {
            int r = idx >> 6, c4 = idx & 63;
            *(float4*)&Ws[r][c4 * 4] = *(const float4*)(W + (size_t)(k0 + r) * 256 + c4 * 4);
        }
        __syncthreads();
#pragma unroll
        for (int kk4 = 0; kk4 < 8; kk4++) {
            float4 xq[8];
#pragma unroll
            for (int i = 0; i < 8; i++) xq[i] = *(float4*)&xs[wv * 8 + i][k0 + kk4 * 4];
#pragma unroll
            for (int q = 0; q < 4; q++) {
                float4 w4 = *(float4*)&Ws[kk4 * 4 + q][lane * 4];
#pragma unroll
                for (int i = 0; i < 8; i++) {
                    float xv = (q == 0) ? xq[i].x : (q == 1) ? xq[i].y : (q == 2) ? xq[i].z : xq[i].w;
                    acc[i].x += xv * w4.x;
                    acc[i].y += xv * w4.y;
                    acc[i].z += xv * w4.z;
                    acc[i].w += xv * w4.w;
                }
            }
        }
    }

    float4 as4 = *(const float4*)(a_src + lane * 4);
    float4 ad4 = *(const float4*)(a_dst + lane * 4);
    int hd = lane >> 4, cl = lane & 15;
    size_t nb = (size_t)b * N_NODES;
#pragma unroll
    for (int i = 0; i < 8; i++) {
        int n = node0 + wv * 8 + i;
        if (n >= N_NODES) break;
        // head-major store: h2[((b*4+hd)*N + n)*64 + cl*4]
        *(float4*)(h2 + ((size_t)(b * 4 + hd) * N_NODES + n) * 64 + cl * 4) = acc[i];
        float vs = acc[i].x * as4.x + acc[i].y * as4.y + acc[i].z * as4.z + acc[i].w * as4.w;
        float vd = acc[i].x * ad4.x + acc[i].y * ad4.y + acc[i].z * ad4.z + acc[i].w * ad4.w;
#pragma unroll
        for (int o = 1; o < 16; o <<= 1) {
            vs += __shfl_xor(vs, o);
            vd += __shfl_xor(vd, o);
        }
        if (cl == 0) {
            alsrc[(nb + n) * 4 + hd] = vs;
            aldst[(nb + n) * 4 + hd] = vd;
        }
    }
}

// ---------------- Fused softmax + per-head aggregation ----------------
// 1-D grid of 16 combos (batch, head) x 625 blocks, swizzled so each combo's
// blocks land on one XCD (round-robin bid%8) -> per-XCD L2 working set = 2.56 MB.
// Block: 4 waves x 4 groups of 16 lanes; each group owns one dst, lane cl covers
// channels cl*4..cl*4+3 of head hd. Per edge: 256 B contiguous gather per group.

__launch_bounds__(256)
__global__ void k_agg(const float* __restrict__ h2, const float* __restrict__ alsrc,
                      const float* __restrict__ aldst, const int* __restrict__ offs,
                      const int* __restrict__ csr, float* __restrict__ oh) {
    int t = threadIdx.x;
    int bid = blockIdx.x;
    int combo = (bid & 7) + 8 * (bid / 5000);
    int local = (bid >> 3) % 625;
    int b = combo & 3, hd = combo >> 2;
    int wv = t >> 6, lane = t & 63;
    int sg = lane >> 4, cl = lane & 15;
    int dst = local * 16 + wv * 4 + sg;

    size_t nb = (size_t)b * N_NODES;
    const float* als = alsrc + nb * 4;
    const float* hc = h2 + (size_t)(b * 4 + hd) * N_NODES * 64;

    float ad_h = aldst[(nb + dst) * 4 + hd];
    int s0 = offs[dst], s1 = offs[dst + 1];

    // pass 1: per-head max, 16 lanes stride the edge list
    float m = -1e30f;
    for (int j = s0 + cl; j < s1; j += 16) {
        int src = csr[j];
        float a = als[(size_t)src * 4 + hd] + ad_h;
        a = a > 0.f ? a : NEG_SLOPE * a;
        m = fmaxf(m, a);
    }
#pragma unroll
    for (int o = 1; o < 16; o <<= 1) m = fmaxf(m, __shfl_xor(m, o));

    // pass 2: all 16 lanes walk edges together; 256 B contiguous h row per edge
    float4 acc = make_float4(0.f, 0.f, 0.f, 0.f);
    float sacc = 0.f;
#pragma unroll 4
    for (int j = s0; j < s1; j++) {
        int src = csr[j];
        float a = als[(size_t)src * 4 + hd] + ad_h;
        a = a > 0.f ? a : NEG_SLOPE * a;
        float p = __expf(a - m);
        float4 h4 = *(const float4*)(hc + (size_t)src * 64 + cl * 4);
        acc.x += p * h4.x;
        acc.y += p * h4.y;
        acc.z += p * h4.z;
        acc.w += p * h4.w;
        sacc += p;
    }
    float inv = 1.f / (sacc + 1e-16f);
    acc.x *= inv; acc.y *= inv; acc.z *= inv; acc.w *= inv;
    *(float4*)(oh + ((size_t)(b * 4 + hd) * N_NODES + dst) * 64 + cl * 4) = acc;
}

// ---------------- Head mean + bias (+ELU for layer 1): pure streaming ----------------

template <bool LAYER1>
__launch_bounds__(256)
__global__ void k_reduce(const float* __restrict__ oh, const float* __restrict__ bias,
                         float* __restrict__ out) {
    int tid = blockIdx.x * 256 + threadIdx.x;  // B*N*16 threads, one float4 each
    int c4 = (tid & 15) * 4;
    int n = (tid >> 4) % N_NODES;
    int b = tid / (N_NODES * 16);
    size_t base = ((size_t)(b * 4) * N_NODES + n) * 64 + c4;
    float4 s = make_float4(0.f, 0.f, 0.f, 0.f);
#pragma unroll
    for (int hd = 0; hd < 4; hd++) {
        float4 v = *(const float4*)(oh + base + (size_t)hd * N_NODES * 64);
        s.x += v.x; s.y += v.y; s.z += v.z; s.w += v.w;
    }
    float4 b4 = *(const float4*)(bias + c4);
    float ox = s.x * 0.25f + b4.x;
    float oy = s.y * 0.25f + b4.y;
    float oz = s.z * 0.25f + b4.z;
    float ow = s.w * 0.25f + b4.w;
    if (LAYER1) {
        ox = ox > 0.f ? ox : expm1f(ox);
        oy = oy > 0.f ? oy : expm1f(oy);
        oz = oz > 0.f ? oz : expm1f(oz);
        ow = ow > 0.f ? ow : expm1f(ow);
    }
    *(float4*)(out + ((size_t)b * N_NODES + n) * 64 + c4) = make_float4(ox, oy, oz, ow);
}

// ---------------- Launch ----------------

extern "C" void kernel_launch(void* const* d_in, const int* in_sizes, int n_in,
                              void* d_out, int out_size, void* d_ws, size_t ws_size,
                              hipStream_t stream) {
    const float* x = (const float*)d_in[0];
    const int* ei = (const int*)d_in[1];
    const float* W1 = (const float*)d_in[2];
    const float* as1 = (const float*)d_in[3];
    const float* ad1 = (const float*)d_in[4];
    const float* b1 = (const float*)d_in[5];
    const float* W2 = (const float*)d_in[6];
    const float* as2 = (const float*)d_in[7];
    const float* ad2 = (const float*)d_in[8];
    const float* b2 = (const float*)d_in[9];
    float* out = (float*)d_out;

    // workspace layout
    char* p = (char*)d_ws;
    int* deg = (int*)p;            p += sizeof(int) * N_NODES;
    int* offs = (int*)p;           p += sizeof(int) * (N_NODES + 1);
    int* cursor = (int*)p;         p += sizeof(int) * N_NODES;
    int* csr = (int*)p;            p += sizeof(int) * E_TOT;
    float* alsrc = (float*)p;      p += sizeof(float) * B_BATCH * N_NODES * 4;
    float* aldst = (float*)p;      p += sizeof(float) * B_BATCH * N_NODES * 4;
    float* h2 = (float*)p;         p += sizeof(float) * (size_t)B_BATCH * N_NODES * 256;
    float* oh = (float*)p;         p += sizeof(float) * (size_t)B_BATCH * N_NODES * 256;
    float* x2 = (float*)p;         p += sizeof(float) * (size_t)B_BATCH * N_NODES * 64;

    // CSR build
    k_deg_init<<<(N_NODES + 255) / 256, 256, 0, stream>>>(deg);
    k_deg_count<<<(E_EDGES + 255) / 256, 256, 0, stream>>>(ei, deg);
    k_scan<<<1, 1024, 0, stream>>>(deg, offs, cursor);
    k_scatter<<<(E_TOT + 255) / 256, 256, 0, stream>>>(ei, cursor, csr);

    dim3 gGemm((N_NODES + 31) / 32, B_BATCH);
    int gAgg = 16 * 625;          // (batch, head) combos x 625 blocks, XCD-swizzled
    int gRed = B_BATCH * N_NODES * 16 / 256;

    // Layer 1
    k_gemm<F_IN_C><<<gGemm, 256, 0, stream>>>(x, W1, as1, ad1, h2, alsrc, aldst);
    k_agg<<<gAgg, 256, 0, stream>>>(h2, alsrc, aldst, offs, csr, oh);
    k_reduce<true><<<gRed, 256, 0, stream>>>(oh, b1, x2);

    // Layer 2
    k_gemm<HID_C><<<gGemm, 256, 0, stream>>>(x2, W2, as2, ad2, h2, alsrc, aldst);
    k_agg<<<gAgg, 256, 0, stream>>>(h2, alsrc, aldst, offs, csr, oh);
    k_reduce<false><<<gRed, 256, 0, stream>>>(oh, b2, out);
}